// Round 2
// baseline (935.582 us; speedup 1.0000x reference)
//
#include <hip/hip_runtime.h>
#include <hip/hip_bf16.h>

// ---------------- problem constants ----------------
#define HW    4096      // H*W
#define BB    8         // batch
#define TT    8         // time steps

// ws layout (in floats)
constexpr int OFF_SBUF  = 0;                   // 8*64*4096 = 2097152 floats
constexpr int OFF_WFRAG = 2097152;             // 34 frags * 64 lanes * 16B = 8704 floats
constexpr int OFF_WTOUT = OFF_WFRAG + 8704;    // 4096 floats (Wt_out[c][o])
constexpr int OFF_WXB   = OFF_WTOUT + 4096;    // 256 float2 = 512 floats {w_x, bias}

typedef _Float16 halfx8 __attribute__((ext_vector_type(8)));
typedef float    floatx4 __attribute__((ext_vector_type(4)));
typedef float    floatx2 __attribute__((ext_vector_type(2)));

__device__ inline float fast_exp2(float x) {
#if __has_builtin(__builtin_amdgcn_exp2f)
    return __builtin_amdgcn_exp2f(x);
#else
    return __builtin_exp2f(x);
#endif
}
__device__ inline float fast_rcp(float x) {
#if __has_builtin(__builtin_amdgcn_rcpf)
    return __builtin_amdgcn_rcpf(x);
#else
    return 1.0f / x;
#endif
}
__device__ inline floatx2 exp2x2(floatx2 x) {
    floatx2 r; r.x = fast_exp2(x.x); r.y = fast_exp2(x.y); return r;
}
__device__ inline floatx2 rcpx2(floatx2 x) {
    floatx2 r; r.x = fast_rcp(x.x); r.y = fast_rcp(x.y); return r;
}
__device__ inline floatx2 fsig2(floatx2 x) {          // sigmoid
    return rcpx2(exp2x2(x * -1.44269504088896f) + 1.0f);
}
__device__ inline floatx2 ftanh2(floatx2 x) {         // tanh
    floatx2 r = rcpx2(exp2x2(x * 2.88539008177793f) + 1.0f);
    return r * -2.0f + 1.0f;
}

union h16u { _Float16 f; unsigned short u; };
union pack8 { _Float16 h[8]; uint4 u; };

// ---------------- prep: repack weights into d_ws (2 blocks) ----------------
__global__ __launch_bounds__(256) void prep_kernel(
    const float* __restrict__ w_ih,  const float* __restrict__ w_hh,
    const float* __restrict__ b_ih,  const float* __restrict__ b_hh,
    const float* __restrict__ w_s,   const float* __restrict__ w_out,
    float* __restrict__ ws_f) {
    int tid = threadIdx.x;
    if (blockIdx.x == 0) {
        // w_hh -> B-fragment-ordered f16. frag fi = nb*2+kc; entry e = fi*64 + lane.
        // lane l holds B[k = kc*32+(l>>4)*8 + j][n=(l&15)]: w_hh[gate=(l&15)+16*nb][hid=k]
        uint4* wf = (uint4*)(ws_f + OFF_WFRAG);
        #pragma unroll
        for (int i = 0; i < 8; ++i) {
            int e  = tid + 256 * i;
            int l  = e & 63;
            int fi = e >> 6;
            int nb = fi >> 1, kc = fi & 1;
            int gate = (l & 15) + 16 * nb;
            int hid  = kc * 32 + (l >> 4) * 8;
            const float* src = w_hh + gate * 64 + hid;
            pack8 p;
            #pragma unroll
            for (int j = 0; j < 8; ++j) p.h[j] = (_Float16)src[j];
            wf[e] = p.u;
        }
        // s-projection fragments (frags 32,33): B[k][0] = w_s[k], other cols 0
        if (tid < 128) {
            int l = tid & 63, kc = tid >> 6;
            pack8 p;
            #pragma unroll
            for (int j = 0; j < 8; ++j) p.h[j] = (_Float16)0.0f;
            if ((l & 15) == 0) {
                #pragma unroll
                for (int j = 0; j < 8; ++j)
                    p.h[j] = (_Float16)w_s[kc * 32 + (l >> 4) * 8 + j];
            }
            wf[2048 + kc * 64 + l] = p.u;
        }
    } else {
        // transposed conv-out weights: Wt[c][o] = w_out[o][c]
        #pragma unroll
        for (int i = 0; i < 16; ++i) {
            int idx = tid + 256 * i;
            int o = idx & 63, c = idx >> 6;
            ws_f[OFF_WTOUT + idx] = w_out[o * 64 + c];
        }
        // {w_x, bias} pairs
        floatx2* wxb = (floatx2*)(ws_f + OFF_WXB);
        floatx2 v; v.x = w_ih[tid]; v.y = b_ih[tid] + b_hh[tid];
        wxb[tid] = v;
    }
}

// ---------------- fused conv_in + per-pixel LSTM ----------------
// 1 wave = 16 sequences (pixels). gates(16x256) = h(16x64) @ w_hh^T via mfma 16x16x32 f16.
// D layout: lane l, reg r -> seq=(l>>4)*4+r, gate=(l&15)+16*nb.
// A layout: lane l -> seq=l&15, hid=(l>>4)*8+j (+32 for chunk 1).
__global__ __launch_bounds__(256, 3) void lstm_kernel(
    const float* __restrict__ hin,    // (B, 64, HW) original input h
    const float* __restrict__ ws_f,   // tables
    float* __restrict__ s_buf,        // (B, 64, HW) output s values
    const float* __restrict__ w_in,   // (64, 64)
    const float* __restrict__ b_in,   // (64,)
    const float* __restrict__ b_s_p) {
    __shared__ uint4 wfrag_lds[2176];                 // 34816 B: 32 w_hh frags + 2 w_s frags
    __shared__ __align__(16) float x_lds[512];        // 2048 B: [t][seq_local]
    __shared__ floatx2 w8p[256];                      // 2048 B: [c][tq] = {w_in[g8+tq][c], w_in[g8+tq+4][c]}
    __shared__ floatx2 wxb_lds[256];                  // 2048 B: per-gate {w_x, bias}
    __shared__ __align__(16) unsigned char uni[9216]; // union: h_stage (8 KB) / h_lds (9 KB)
    unsigned short* h_lds   = (unsigned short*)uni;   // 4 waves x 16 rows x 72 f16 (144 B rows)
    float*          h_stage = (float*)uni;            // 32 x 64 fp32

    int tid = threadIdx.x;
    int bg    = blockIdx.x & 63;          // b*8+g  (consecutive blocks share pixels -> L2 reuse of hin)
    int ptile = blockIdx.x >> 6;
    int b = bg >> 3, g = bg & 7;
    int p0 = ptile * 64;

    // stage weight fragments (shared by all 4 waves)
    const uint4* wfg = (const uint4*)(ws_f + OFF_WFRAG);
    #pragma unroll
    for (int i = 0; i < 9; ++i) {
        int e = tid + 256 * i;
        if (e < 2176) wfrag_lds[e] = wfg[e];
    }
    // stage per-gate {w_x, bias}
    wxb_lds[tid] = ((const floatx2*)(ws_f + OFF_WXB))[tid];
    // stage conv-in weight pairs: e = c*4+tq
    {
        int c = tid >> 2, tq = tid & 3;
        floatx2 v;
        v.x = w_in[(g * 8 + tq) * 64 + c];
        v.y = w_in[(g * 8 + tq + 4) * 64 + c];
        w8p[tid] = v;
    }

    // ---- fused conv_in: x[t][px] = sum_c w_in[g*8+t][c]*hin[b][c][p0+px] + b_in ----
    int px = tid & 63, tq = tid >> 6;     // each thread -> outputs (t=tq, t=tq+4) for pixel px
    floatx2 xacc; xacc.x = b_in[g * 8 + tq]; xacc.y = b_in[g * 8 + tq + 4];
    #pragma unroll
    for (int pass = 0; pass < 2; ++pass) {
        __syncthreads();                  // w8p ready (pass 0) / h_stage reads done (pass 1)
        #pragma unroll
        for (int i = 0; i < 2; ++i) {
            int e  = tid + 256 * i;       // 512 float4 per pass
            int cc = e >> 4, f4 = e & 15;
            ((floatx4*)h_stage)[e] =
                *(const floatx4*)&hin[(b * 64 + pass * 32 + cc) * HW + p0 + f4 * 4];
        }
        __syncthreads();
        #pragma unroll 8
        for (int cc = 0; cc < 32; ++cc) {
            float hv = h_stage[cc * 64 + px];
            floatx2 w = w8p[(pass * 32 + cc) * 4 + tq];
            floatx2 h2; h2.x = hv; h2.y = hv;
            xacc = xacc + w * h2;
        }
    }
    __syncthreads();                      // h_stage reads done before x write / h_lds zero
    x_lds[tq * 64 + px]       = xacc.x;
    x_lds[(tq + 4) * 64 + px] = xacc.y;
    // zero h state (aliases h_stage)
    #pragma unroll
    for (int i = 0; i < 9; ++i) {
        int idx = tid + 256 * i;
        if (idx < 2304) ((unsigned*)uni)[idx] = 0u;
    }
    __syncthreads();

    int lane = tid & 63;
    int wv   = tid >> 6;
    int s    = lane & 15;
    int q    = lane >> 4;

    unsigned short* hrow = h_lds + wv * 16 * 72;
    int pw = p0 + wv * 16;
    float bs = b_s_p[0];

    // s-projection B fragments (only 2 -> keep in regs)
    halfx8 sb0 = *(const halfx8*)&wfrag_lds[32 * 64 + lane];
    halfx8 sb1 = *(const halfx8*)&wfrag_lds[33 * 64 + lane];

    float c_st[4][4];
    #pragma unroll
    for (int hb = 0; hb < 4; ++hb)
        #pragma unroll
        for (int r = 0; r < 4; ++r) c_st[hb][r] = 0.0f;

    for (int t = 0; t < TT; ++t) {
        halfx8 a0 = *(const halfx8*)(hrow + s * 72 + q * 8);        // k = 0..31
        halfx8 a1 = *(const halfx8*)(hrow + s * 72 + q * 8 + 32);   // k = 32..63

        // s_{t-1} = h_t @ w_s via MFMA (col 0 only); lanes s==0 hold seq q*4+r
        if (t > 0) {
            floatx4 sa = {0.f, 0.f, 0.f, 0.f};
            sa = __builtin_amdgcn_mfma_f32_16x16x32_f16(a0, sb0, sa, 0, 0, 0);
            sa = __builtin_amdgcn_mfma_f32_16x16x32_f16(a1, sb1, sa, 0, 0, 0);
            if (s == 0) {
                floatx4 o4 = {sa[0] + bs, sa[1] + bs, sa[2] + bs, sa[3] + bs};
                *(floatx4*)&s_buf[(bg * 8 + (t - 1)) * HW + pw + q * 4] = o4;
            }
        }

        floatx4 xv = *(const floatx4*)&x_lds[t * 64 + wv * 16 + q * 4];
        floatx2 xlo; xlo.x = xv[0]; xlo.y = xv[1];
        floatx2 xhi; xhi.x = xv[2]; xhi.y = xv[3];

        #pragma unroll
        for (int hb = 0; hb < 4; ++hb) {
            floatx4 acc[4];
            #pragma unroll
            for (int gi = 0; gi < 4; ++gi) {
                int nb = hb + 4 * gi;
                floatx2 wb = wxb_lds[s + 16 * nb];
                floatx2 lo = xlo * wb.x + wb.y;     // x*w_x + bias as C init (pk_fma)
                floatx2 hi = xhi * wb.x + wb.y;
                floatx4 a = {lo.x, lo.y, hi.x, hi.y};
                halfx8 b0 = *(const halfx8*)&wfrag_lds[(nb * 2 + 0) * 64 + lane];
                halfx8 b1 = *(const halfx8*)&wfrag_lds[(nb * 2 + 1) * 64 + lane];
                a = __builtin_amdgcn_mfma_f32_16x16x32_f16(a0, b0, a, 0, 0, 0);
                a = __builtin_amdgcn_mfma_f32_16x16x32_f16(a1, b1, a, 0, 0, 0);
                acc[gi] = a;
            }
            int s16 = s + 16 * hb;
            #pragma unroll
            for (int p = 0; p < 2; ++p) {
                int r0 = 2 * p;
                floatx2 iv; iv.x = acc[0][r0]; iv.y = acc[0][r0 + 1]; iv = fsig2(iv);
                floatx2 fv; fv.x = acc[1][r0]; fv.y = acc[1][r0 + 1]; fv = fsig2(fv);
                floatx2 gv; gv.x = acc[2][r0]; gv.y = acc[2][r0 + 1]; gv = ftanh2(gv);
                floatx2 ov; ov.x = acc[3][r0]; ov.y = acc[3][r0 + 1]; ov = fsig2(ov);
                floatx2 cp; cp.x = c_st[hb][r0]; cp.y = c_st[hb][r0 + 1];
                floatx2 c = fv * cp + iv * gv;
                c_st[hb][r0] = c.x; c_st[hb][r0 + 1] = c.y;
                floatx2 hn = ov * ftanh2(c);
                h16u u0, u1;
                u0.f = (_Float16)hn.x;
                u1.f = (_Float16)hn.y;
                hrow[(q * 4 + r0) * 72 + s16]     = u0.u;   // state for t+1
                hrow[(q * 4 + r0 + 1) * 72 + s16] = u1.u;
            }
        }
    }
    // final s_7 from h_8
    {
        halfx8 a0 = *(const halfx8*)(hrow + s * 72 + q * 8);
        halfx8 a1 = *(const halfx8*)(hrow + s * 72 + q * 8 + 32);
        floatx4 sa = {0.f, 0.f, 0.f, 0.f};
        sa = __builtin_amdgcn_mfma_f32_16x16x32_f16(a0, sb0, sa, 0, 0, 0);
        sa = __builtin_amdgcn_mfma_f32_16x16x32_f16(a1, sb1, sa, 0, 0, 0);
        if (s == 0) {
            floatx4 o4 = {sa[0] + bs, sa[1] + bs, sa[2] + bs, sa[3] + bs};
            *(floatx4*)&s_buf[(bg * 8 + 7) * HW + pw + q * 4] = o4;
        }
    }
}

// ---------------- conv_out: 1x1 conv with pk-fma ----------------
__global__ __launch_bounds__(256) void conv_out_kernel(
    const float* __restrict__ x, const float* __restrict__ Wt,
    const float* __restrict__ bias, float* __restrict__ y) {
    int p  = blockIdx.x * 256 + threadIdx.x;
    int b  = blockIdx.y;
    int oh = blockIdx.z;                  // outputs [32*oh, 32*oh+32)
    const float* xb = x + b * 64 * HW;
    const floatx2* Wt2 = (const floatx2*)Wt;  // row c: 32 float2 pairs
    floatx2 acc[16];
    #pragma unroll
    for (int j = 0; j < 16; ++j) { acc[j].x = 0.f; acc[j].y = 0.f; }
    #pragma unroll 4
    for (int c = 0; c < 64; ++c) {
        float hv = xb[c * HW + p];
        floatx2 h2; h2.x = hv; h2.y = hv;
        #pragma unroll
        for (int j = 0; j < 16; ++j)
            acc[j] = acc[j] + Wt2[c * 32 + oh * 16 + j] * h2;
    }
    float* yb = y + b * 64 * HW + oh * 32 * HW;
    #pragma unroll
    for (int j = 0; j < 16; ++j) {
        yb[(2 * j) * HW + p]     = acc[j].x + bias[oh * 32 + 2 * j];
        yb[(2 * j + 1) * HW + p] = acc[j].y + bias[oh * 32 + 2 * j + 1];
    }
}

extern "C" void kernel_launch(void* const* d_in, const int* in_sizes, int n_in,
                              void* d_out, int out_size, void* d_ws, size_t ws_size,
                              hipStream_t stream) {
    const float* h     = (const float*)d_in[0];
    const float* w_in  = (const float*)d_in[1];
    const float* b_in  = (const float*)d_in[2];
    const float* w_ih  = (const float*)d_in[3];
    const float* w_hh  = (const float*)d_in[4];
    const float* b_ih  = (const float*)d_in[5];
    const float* b_hh  = (const float*)d_in[6];
    const float* w_s   = (const float*)d_in[7];
    const float* b_s   = (const float*)d_in[8];
    const float* w_out = (const float*)d_in[9];
    const float* b_out = (const float*)d_in[10];
    float* out = (float*)d_out;
    float* ws  = (float*)d_ws;

    prep_kernel<<<2, 256, 0, stream>>>(w_ih, w_hh, b_ih, b_hh, w_s, w_out, ws);
    // fused conv_in + LSTM: hin -> s_buf (ws)
    lstm_kernel<<<4096, 256, 0, stream>>>(h, ws, ws + OFF_SBUF, w_in, b_in, b_s);
    // conv_out: s_buf -> d_out
    conv_out_kernel<<<dim3(16, BB, 2), 256, 0, stream>>>(ws + OFF_SBUF, ws + OFF_WTOUT, b_out, out);
}

// Round 3
// 468.478 us; speedup vs baseline: 1.9971x; 1.9971x over previous
//
#include <hip/hip_runtime.h>
#include <hip/hip_bf16.h>

// ---------------- problem constants ----------------
#define HW    4096      // H*W
#define BB    8         // batch
#define TT    8         // time steps

// ws layout (in floats)
constexpr int OFF_SBUF  = 0;                   // 8*64*4096 = 2097152 floats
constexpr int OFF_WFRAG = 2097152;             // 34 frags * 64 lanes * 16B = 8704 floats
constexpr int OFF_WTOUT = OFF_WFRAG + 8704;    // 4096 floats (Wt_out[c][o])
constexpr int OFF_WXB   = OFF_WTOUT + 4096;    // 256 float2 = 512 floats {w_x, bias}

typedef _Float16 halfx8 __attribute__((ext_vector_type(8)));
typedef float    floatx4 __attribute__((ext_vector_type(4)));
typedef float    floatx2 __attribute__((ext_vector_type(2)));

__device__ inline float fast_exp2(float x) {
#if __has_builtin(__builtin_amdgcn_exp2f)
    return __builtin_amdgcn_exp2f(x);
#else
    return __builtin_exp2f(x);
#endif
}
__device__ inline float fast_rcp(float x) {
#if __has_builtin(__builtin_amdgcn_rcpf)
    return __builtin_amdgcn_rcpf(x);
#else
    return 1.0f / x;
#endif
}
__device__ inline floatx2 exp2x2(floatx2 x) {
    floatx2 r; r.x = fast_exp2(x.x); r.y = fast_exp2(x.y); return r;
}
__device__ inline floatx2 rcpx2(floatx2 x) {
    floatx2 r; r.x = fast_rcp(x.x); r.y = fast_rcp(x.y); return r;
}
__device__ inline floatx2 fsig2(floatx2 x) {          // sigmoid
    return rcpx2(exp2x2(x * -1.44269504088896f) + 1.0f);
}
__device__ inline floatx2 ftanh2(floatx2 x) {         // tanh
    floatx2 r = rcpx2(exp2x2(x * 2.88539008177793f) + 1.0f);
    return r * -2.0f + 1.0f;
}

union h16u { _Float16 f; unsigned short u; };
union pack8 { _Float16 h[8]; uint4 u; };

// ---------------- prep: repack weights into d_ws (2 blocks) ----------------
__global__ __launch_bounds__(256) void prep_kernel(
    const float* __restrict__ w_ih,  const float* __restrict__ w_hh,
    const float* __restrict__ b_ih,  const float* __restrict__ b_hh,
    const float* __restrict__ w_s,   const float* __restrict__ w_out,
    float* __restrict__ ws_f) {
    int tid = threadIdx.x;
    if (blockIdx.x == 0) {
        // w_hh -> B-fragment-ordered f16. frag fi = nb*2+kc; entry e = fi*64 + lane.
        // lane l holds B[k = kc*32+(l>>4)*8 + j][n=(l&15)]: w_hh[gate=(l&15)+16*nb][hid=k]
        uint4* wf = (uint4*)(ws_f + OFF_WFRAG);
        #pragma unroll
        for (int i = 0; i < 8; ++i) {
            int e  = tid + 256 * i;
            int l  = e & 63;
            int fi = e >> 6;
            int nb = fi >> 1, kc = fi & 1;
            int gate = (l & 15) + 16 * nb;
            int hid  = kc * 32 + (l >> 4) * 8;
            const float* src = w_hh + gate * 64 + hid;
            pack8 p;
            #pragma unroll
            for (int j = 0; j < 8; ++j) p.h[j] = (_Float16)src[j];
            wf[e] = p.u;
        }
        // s-projection fragments (frags 32,33): B[k][0] = w_s[k], other cols 0
        if (tid < 128) {
            int l = tid & 63, kc = tid >> 6;
            pack8 p;
            #pragma unroll
            for (int j = 0; j < 8; ++j) p.h[j] = (_Float16)0.0f;
            if ((l & 15) == 0) {
                #pragma unroll
                for (int j = 0; j < 8; ++j)
                    p.h[j] = (_Float16)w_s[kc * 32 + (l >> 4) * 8 + j];
            }
            wf[2048 + kc * 64 + l] = p.u;
        }
    } else {
        // transposed conv-out weights: Wt[c][o] = w_out[o][c]
        #pragma unroll
        for (int i = 0; i < 16; ++i) {
            int idx = tid + 256 * i;
            int o = idx & 63, c = idx >> 6;
            ws_f[OFF_WTOUT + idx] = w_out[o * 64 + c];
        }
        // {w_x, bias} pairs
        floatx2* wxb = (floatx2*)(ws_f + OFF_WXB);
        floatx2 v; v.x = w_ih[tid]; v.y = b_ih[tid] + b_hh[tid];
        wxb[tid] = v;
    }
}

// ---------------- fused conv_in + per-pixel LSTM ----------------
// 1 wave = 16 sequences (pixels). gates(16x256) = h(16x64) @ w_hh^T via mfma 16x16x32 f16.
// D layout: lane l, reg r -> seq=(l>>4)*4+r, gate=(l&15)+16*nb.
// A layout: lane l -> seq=l&15, hid=(l>>4)*8+j (+32 for chunk 1).
// launch_bounds(256,2): round 2 showed (256,3) forces massive scratch spills
// (FETCH 4MB->2.5GB); natural footprint is ~176 VGPR -> 2 waves/SIMD.
__global__ __launch_bounds__(256, 2) void lstm_kernel(
    const float* __restrict__ hin,    // (B, 64, HW) original input h
    const float* __restrict__ ws_f,   // tables
    float* __restrict__ s_buf,        // (B, 64, HW) output s values
    const float* __restrict__ w_in,   // (64, 64)
    const float* __restrict__ b_in,   // (64,)
    const float* __restrict__ b_s_p) {
    __shared__ uint4 wfrag_lds[2176];                 // 34816 B: 32 w_hh frags + 2 w_s frags
    __shared__ __align__(16) float x_lds[512];        // 2048 B: [t][seq_local]
    __shared__ floatx2 w8p[256];                      // 2048 B: [c][tq] = {w_in[g8+tq][c], w_in[g8+tq+4][c]}
    __shared__ floatx2 wxb_lds[256];                  // 2048 B: per-gate {w_x, bias}
    __shared__ __align__(16) unsigned char uni[9216]; // union: h_stage (8 KB) / h_lds (9 KB)
    unsigned short* h_lds   = (unsigned short*)uni;   // 4 waves x 16 rows x 72 f16 (144 B rows)
    float*          h_stage = (float*)uni;            // 32 x 64 fp32

    int tid = threadIdx.x;
    int bg    = blockIdx.x & 63;          // b*8+g  (consecutive blocks share pixels -> L2 reuse of hin)
    int ptile = blockIdx.x >> 6;
    int b = bg >> 3, g = bg & 7;
    int p0 = ptile * 64;

    // stage weight fragments (shared by all 4 waves)
    const uint4* wfg = (const uint4*)(ws_f + OFF_WFRAG);
    #pragma unroll
    for (int i = 0; i < 9; ++i) {
        int e = tid + 256 * i;
        if (e < 2176) wfrag_lds[e] = wfg[e];
    }
    // stage per-gate {w_x, bias}
    wxb_lds[tid] = ((const floatx2*)(ws_f + OFF_WXB))[tid];
    // stage conv-in weight pairs: e = c*4+tq
    {
        int c = tid >> 2, tq = tid & 3;
        floatx2 v;
        v.x = w_in[(g * 8 + tq) * 64 + c];
        v.y = w_in[(g * 8 + tq + 4) * 64 + c];
        w8p[tid] = v;
    }

    // ---- fused conv_in: x[t][px] = sum_c w_in[g*8+t][c]*hin[b][c][p0+px] + b_in ----
    int px = tid & 63, tq = tid >> 6;     // each thread -> outputs (t=tq, t=tq+4) for pixel px
    floatx2 xacc; xacc.x = b_in[g * 8 + tq]; xacc.y = b_in[g * 8 + tq + 4];
    #pragma unroll
    for (int pass = 0; pass < 2; ++pass) {
        __syncthreads();                  // w8p ready (pass 0) / h_stage reads done (pass 1)
        #pragma unroll
        for (int i = 0; i < 2; ++i) {
            int e  = tid + 256 * i;       // 512 float4 per pass
            int cc = e >> 4, f4 = e & 15;
            ((floatx4*)h_stage)[e] =
                *(const floatx4*)&hin[(b * 64 + pass * 32 + cc) * HW + p0 + f4 * 4];
        }
        __syncthreads();
        #pragma unroll 8
        for (int cc = 0; cc < 32; ++cc) {
            float hv = h_stage[cc * 64 + px];
            floatx2 w = w8p[(pass * 32 + cc) * 4 + tq];
            floatx2 h2; h2.x = hv; h2.y = hv;
            xacc = xacc + w * h2;
        }
    }
    __syncthreads();                      // h_stage reads done before x write / h_lds zero
    x_lds[tq * 64 + px]       = xacc.x;
    x_lds[(tq + 4) * 64 + px] = xacc.y;
    // zero h state (aliases h_stage)
    #pragma unroll
    for (int i = 0; i < 9; ++i) {
        int idx = tid + 256 * i;
        if (idx < 2304) ((unsigned*)uni)[idx] = 0u;
    }
    __syncthreads();

    int lane = tid & 63;
    int wv   = tid >> 6;
    int s    = lane & 15;
    int q    = lane >> 4;

    unsigned short* hrow = h_lds + wv * 16 * 72;
    int pw = p0 + wv * 16;
    float bs = b_s_p[0];

    // s-projection B fragments (only 2 -> keep in regs)
    halfx8 sb0 = *(const halfx8*)&wfrag_lds[32 * 64 + lane];
    halfx8 sb1 = *(const halfx8*)&wfrag_lds[33 * 64 + lane];

    float c_st[4][4];
    #pragma unroll
    for (int hb = 0; hb < 4; ++hb)
        #pragma unroll
        for (int r = 0; r < 4; ++r) c_st[hb][r] = 0.0f;

    for (int t = 0; t < TT; ++t) {
        halfx8 a0 = *(const halfx8*)(hrow + s * 72 + q * 8);        // k = 0..31
        halfx8 a1 = *(const halfx8*)(hrow + s * 72 + q * 8 + 32);   // k = 32..63

        // s_{t-1} = h_t @ w_s via MFMA (col 0 only); lanes s==0 hold seq q*4+r
        if (t > 0) {
            floatx4 sa = {0.f, 0.f, 0.f, 0.f};
            sa = __builtin_amdgcn_mfma_f32_16x16x32_f16(a0, sb0, sa, 0, 0, 0);
            sa = __builtin_amdgcn_mfma_f32_16x16x32_f16(a1, sb1, sa, 0, 0, 0);
            if (s == 0) {
                floatx4 o4 = {sa[0] + bs, sa[1] + bs, sa[2] + bs, sa[3] + bs};
                *(floatx4*)&s_buf[(bg * 8 + (t - 1)) * HW + pw + q * 4] = o4;
            }
        }

        floatx4 xv = *(const floatx4*)&x_lds[t * 64 + wv * 16 + q * 4];
        floatx2 xlo; xlo.x = xv[0]; xlo.y = xv[1];
        floatx2 xhi; xhi.x = xv[2]; xhi.y = xv[3];

        #pragma unroll
        for (int hb = 0; hb < 4; ++hb) {
            floatx4 acc[4];
            #pragma unroll
            for (int gi = 0; gi < 4; ++gi) {
                int nb = hb + 4 * gi;
                floatx2 wb = wxb_lds[s + 16 * nb];
                floatx2 lo = xlo * wb.x + wb.y;     // x*w_x + bias as C init (pk_fma)
                floatx2 hi = xhi * wb.x + wb.y;
                floatx4 a = {lo.x, lo.y, hi.x, hi.y};
                halfx8 b0 = *(const halfx8*)&wfrag_lds[(nb * 2 + 0) * 64 + lane];
                halfx8 b1 = *(const halfx8*)&wfrag_lds[(nb * 2 + 1) * 64 + lane];
                a = __builtin_amdgcn_mfma_f32_16x16x32_f16(a0, b0, a, 0, 0, 0);
                a = __builtin_amdgcn_mfma_f32_16x16x32_f16(a1, b1, a, 0, 0, 0);
                acc[gi] = a;
            }
            int s16 = s + 16 * hb;
            #pragma unroll
            for (int p = 0; p < 2; ++p) {
                int r0 = 2 * p;
                floatx2 iv; iv.x = acc[0][r0]; iv.y = acc[0][r0 + 1]; iv = fsig2(iv);
                floatx2 fv; fv.x = acc[1][r0]; fv.y = acc[1][r0 + 1]; fv = fsig2(fv);
                floatx2 gv; gv.x = acc[2][r0]; gv.y = acc[2][r0 + 1]; gv = ftanh2(gv);
                floatx2 ov; ov.x = acc[3][r0]; ov.y = acc[3][r0 + 1]; ov = fsig2(ov);
                floatx2 cp; cp.x = c_st[hb][r0]; cp.y = c_st[hb][r0 + 1];
                floatx2 c = fv * cp + iv * gv;
                c_st[hb][r0] = c.x; c_st[hb][r0 + 1] = c.y;
                floatx2 hn = ov * ftanh2(c);
                h16u u0, u1;
                u0.f = (_Float16)hn.x;
                u1.f = (_Float16)hn.y;
                hrow[(q * 4 + r0) * 72 + s16]     = u0.u;   // state for t+1
                hrow[(q * 4 + r0 + 1) * 72 + s16] = u1.u;
            }
        }
    }
    // final s_7 from h_8
    {
        halfx8 a0 = *(const halfx8*)(hrow + s * 72 + q * 8);
        halfx8 a1 = *(const halfx8*)(hrow + s * 72 + q * 8 + 32);
        floatx4 sa = {0.f, 0.f, 0.f, 0.f};
        sa = __builtin_amdgcn_mfma_f32_16x16x32_f16(a0, sb0, sa, 0, 0, 0);
        sa = __builtin_amdgcn_mfma_f32_16x16x32_f16(a1, sb1, sa, 0, 0, 0);
        if (s == 0) {
            floatx4 o4 = {sa[0] + bs, sa[1] + bs, sa[2] + bs, sa[3] + bs};
            *(floatx4*)&s_buf[(bg * 8 + 7) * HW + pw + q * 4] = o4;
        }
    }
}

// ---------------- conv_out: 1x1 conv with pk-fma ----------------
__global__ __launch_bounds__(256) void conv_out_kernel(
    const float* __restrict__ x, const float* __restrict__ Wt,
    const float* __restrict__ bias, float* __restrict__ y) {
    int p  = blockIdx.x * 256 + threadIdx.x;
    int b  = blockIdx.y;
    int oh = blockIdx.z;                  // outputs [32*oh, 32*oh+32)
    const float* xb = x + b * 64 * HW;
    const floatx2* Wt2 = (const floatx2*)Wt;  // row c: 32 float2 pairs
    floatx2 acc[16];
    #pragma unroll
    for (int j = 0; j < 16; ++j) { acc[j].x = 0.f; acc[j].y = 0.f; }
    #pragma unroll 4
    for (int c = 0; c < 64; ++c) {
        float hv = xb[c * HW + p];
        floatx2 h2; h2.x = hv; h2.y = hv;
        #pragma unroll
        for (int j = 0; j < 16; ++j)
            acc[j] = acc[j] + Wt2[c * 32 + oh * 16 + j] * h2;
    }
    float* yb = y + b * 64 * HW + oh * 32 * HW;
    #pragma unroll
    for (int j = 0; j < 16; ++j) {
        yb[(2 * j) * HW + p]     = acc[j].x + bias[oh * 32 + 2 * j];
        yb[(2 * j + 1) * HW + p] = acc[j].y + bias[oh * 32 + 2 * j + 1];
    }
}

extern "C" void kernel_launch(void* const* d_in, const int* in_sizes, int n_in,
                              void* d_out, int out_size, void* d_ws, size_t ws_size,
                              hipStream_t stream) {
    const float* h     = (const float*)d_in[0];
    const float* w_in  = (const float*)d_in[1];
    const float* b_in  = (const float*)d_in[2];
    const float* w_ih  = (const float*)d_in[3];
    const float* w_hh  = (const float*)d_in[4];
    const float* b_ih  = (const float*)d_in[5];
    const float* b_hh  = (const float*)d_in[6];
    const float* w_s   = (const float*)d_in[7];
    const float* b_s   = (const float*)d_in[8];
    const float* w_out = (const float*)d_in[9];
    const float* b_out = (const float*)d_in[10];
    float* out = (float*)d_out;
    float* ws  = (float*)d_ws;

    prep_kernel<<<2, 256, 0, stream>>>(w_ih, w_hh, b_ih, b_hh, w_s, w_out, ws);
    // fused conv_in + LSTM: hin -> s_buf (ws)
    lstm_kernel<<<4096, 256, 0, stream>>>(h, ws, ws + OFF_SBUF, w_in, b_in, b_s);
    // conv_out: s_buf -> d_out
    conv_out_kernel<<<dim3(16, BB, 2), 256, 0, stream>>>(ws + OFF_SBUF, ws + OFF_WTOUT, b_out, out);
}

// Round 4
// 366.546 us; speedup vs baseline: 2.5524x; 1.2781x over previous
//
#include <hip/hip_runtime.h>
#include <hip/hip_bf16.h>

// ---------------- problem constants ----------------
#define HW    4096      // H*W
#define BB    8         // batch
#define TT    8         // time steps

// ws layout (in floats)
constexpr int OFF_SBUF  = 0;                   // 8*64*4096 = 2097152 floats
constexpr int OFF_WFRAG = 2097152;             // 34 frags * 64 lanes * 16B = 8704 floats
constexpr int OFF_WTOUT = OFF_WFRAG + 8704;    // 4096 floats (Wt_out[c][o])
constexpr int OFF_WXB   = OFF_WTOUT + 4096;    // 256 float2 = 512 floats {w_x, bias}

typedef _Float16 halfx8 __attribute__((ext_vector_type(8)));
typedef float    floatx4 __attribute__((ext_vector_type(4)));
typedef float    floatx2 __attribute__((ext_vector_type(2)));

__device__ inline float fast_exp2(float x) {
#if __has_builtin(__builtin_amdgcn_exp2f)
    return __builtin_amdgcn_exp2f(x);
#else
    return __builtin_exp2f(x);
#endif
}
__device__ inline float fast_rcp(float x) {
#if __has_builtin(__builtin_amdgcn_rcpf)
    return __builtin_amdgcn_rcpf(x);
#else
    return 1.0f / x;
#endif
}
__device__ inline floatx2 exp2x2(floatx2 x) {
    floatx2 r; r.x = fast_exp2(x.x); r.y = fast_exp2(x.y); return r;
}
__device__ inline floatx2 rcpx2(floatx2 x) {
    floatx2 r; r.x = fast_rcp(x.x); r.y = fast_rcp(x.y); return r;
}
__device__ inline floatx2 fsig2(floatx2 x) {          // sigmoid
    return rcpx2(exp2x2(x * -1.44269504088896f) + 1.0f);
}
__device__ inline floatx2 ftanh2(floatx2 x) {         // tanh
    floatx2 r = rcpx2(exp2x2(x * 2.88539008177793f) + 1.0f);
    return r * -2.0f + 1.0f;
}

union h16u { _Float16 f; unsigned short u; };
union pack8 { _Float16 h[8]; uint4 u; };

// ---------------- prep: repack weights into d_ws (2 blocks) ----------------
__global__ __launch_bounds__(256) void prep_kernel(
    const float* __restrict__ w_ih,  const float* __restrict__ w_hh,
    const float* __restrict__ b_ih,  const float* __restrict__ b_hh,
    const float* __restrict__ w_s,   const float* __restrict__ w_out,
    float* __restrict__ ws_f) {
    int tid = threadIdx.x;
    if (blockIdx.x == 0) {
        // w_hh -> B-fragment-ordered f16. frag fi = nb*2+kc; entry e = fi*64 + lane.
        // lane l holds B[k = kc*32+(l>>4)*8 + j][n=(l&15)]: w_hh[gate=(l&15)+16*nb][hid=k]
        uint4* wf = (uint4*)(ws_f + OFF_WFRAG);
        #pragma unroll
        for (int i = 0; i < 8; ++i) {
            int e  = tid + 256 * i;
            int l  = e & 63;
            int fi = e >> 6;
            int nb = fi >> 1, kc = fi & 1;
            int gate = (l & 15) + 16 * nb;
            int hid  = kc * 32 + (l >> 4) * 8;
            const float* src = w_hh + gate * 64 + hid;
            pack8 p;
            #pragma unroll
            for (int j = 0; j < 8; ++j) p.h[j] = (_Float16)src[j];
            wf[e] = p.u;
        }
        // s-projection fragments (frags 32,33): B[k][0] = w_s[k], other cols 0
        if (tid < 128) {
            int l = tid & 63, kc = tid >> 6;
            pack8 p;
            #pragma unroll
            for (int j = 0; j < 8; ++j) p.h[j] = (_Float16)0.0f;
            if ((l & 15) == 0) {
                #pragma unroll
                for (int j = 0; j < 8; ++j)
                    p.h[j] = (_Float16)w_s[kc * 32 + (l >> 4) * 8 + j];
            }
            wf[2048 + kc * 64 + l] = p.u;
        }
    } else {
        // transposed conv-out weights: Wt[c][o] = w_out[o][c]
        #pragma unroll
        for (int i = 0; i < 16; ++i) {
            int idx = tid + 256 * i;
            int o = idx & 63, c = idx >> 6;
            ws_f[OFF_WTOUT + idx] = w_out[o * 64 + c];
        }
        // {w_x, bias} pairs
        floatx2* wxb = (floatx2*)(ws_f + OFF_WXB);
        floatx2 v; v.x = w_ih[tid]; v.y = b_ih[tid] + b_hh[tid];
        wxb[tid] = v;
    }
}

// ---------------- fused conv_in + per-pixel LSTM ----------------
// 1 wave = 16 sequences (pixels). gates(16x256) = h(16x64) @ w_hh^T via mfma 16x16x32 f16.
// D layout: lane l, reg r -> seq=(l>>4)*4+r, gate=(l&15)+16*nb.
// A layout: lane l -> seq=l&15, hid=(l>>4)*8+j (+32 for chunk 1).
// NOTE: natural register allocation ONLY. Any forced min-waves bound makes the
// compiler split the budget half arch-VGPR / half AGPR and spill ~260B/thread
// (r2: (256,3) -> 84 VGPR, 2.5GB scratch; r3: (256,2) -> 128 VGPR, 260MB scratch).
__global__ __launch_bounds__(256) void lstm_kernel(
    const float* __restrict__ hin,    // (B, 64, HW) original input h
    const float* __restrict__ ws_f,   // tables
    float* __restrict__ s_buf,        // (B, 64, HW) output s values
    const float* __restrict__ w_in,   // (64, 64)
    const float* __restrict__ b_in,   // (64,)
    const float* __restrict__ b_s_p) {
    __shared__ __align__(16) float x_lds[512];        // 2048 B: [t][seq_local]
    __shared__ floatx2 w8p[256];                      // 2048 B: [c][tq] = {w_in[g8+tq][c], w_in[g8+tq+4][c]}
    __shared__ floatx2 wxb_lds[256];                  // 2048 B: per-gate {w_x, bias}
    __shared__ __align__(16) unsigned char uni[9216]; // union: h_stage (8 KB) / h_lds (9 KB)
    unsigned short* h_lds   = (unsigned short*)uni;   // 4 waves x 16 rows x 72 f16 (144 B rows)
    float*          h_stage = (float*)uni;            // 32 x 64 fp32

    int tid = threadIdx.x;
    int bg    = blockIdx.x & 63;          // b*8+g
    int ptile = blockIdx.x >> 6;
    int b = bg >> 3, g = bg & 7;
    int p0 = ptile * 64;

    int lane = tid & 63;
    int wv   = tid >> 6;
    int s    = lane & 15;
    int q    = lane >> 4;

    // ---- all 34 B-fragments: global -> registers, held live across the t-loop.
    // 34 x global_load_dwordx4, coalesced (64 lanes x 16 B contiguous per frag),
    // L2-resident after first touch. Removes all per-step LDS B-frag reads.
    halfx8 bfr[34];
    {
        const uint4* wfg = (const uint4*)(ws_f + OFF_WFRAG);
        #pragma unroll
        for (int i = 0; i < 34; ++i)
            bfr[i] = *(const halfx8*)&wfg[i * 64 + lane];
    }

    // stage per-gate {w_x, bias}
    wxb_lds[tid] = ((const floatx2*)(ws_f + OFF_WXB))[tid];
    // stage conv-in weight pairs: e = c*4+tq
    {
        int c = tid >> 2, tq_ = tid & 3;
        floatx2 v;
        v.x = w_in[(g * 8 + tq_) * 64 + c];
        v.y = w_in[(g * 8 + tq_ + 4) * 64 + c];
        w8p[tid] = v;
    }

    // ---- fused conv_in: x[t][px] = sum_c w_in[g*8+t][c]*hin[b][c][p0+px] + b_in ----
    int px = tid & 63, tq = tid >> 6;     // each thread -> outputs (t=tq, t=tq+4) for pixel px
    floatx2 xacc; xacc.x = b_in[g * 8 + tq]; xacc.y = b_in[g * 8 + tq + 4];
    #pragma unroll
    for (int pass = 0; pass < 2; ++pass) {
        __syncthreads();                  // w8p ready (pass 0) / h_stage reads done (pass 1)
        #pragma unroll
        for (int i = 0; i < 2; ++i) {
            int e  = tid + 256 * i;       // 512 float4 per pass
            int cc = e >> 4, f4 = e & 15;
            ((floatx4*)h_stage)[e] =
                *(const floatx4*)&hin[(b * 64 + pass * 32 + cc) * HW + p0 + f4 * 4];
        }
        __syncthreads();
        #pragma unroll 8
        for (int cc = 0; cc < 32; ++cc) {
            float hv = h_stage[cc * 64 + px];
            floatx2 w = w8p[(pass * 32 + cc) * 4 + tq];
            floatx2 h2; h2.x = hv; h2.y = hv;
            xacc = xacc + w * h2;
        }
    }
    __syncthreads();                      // h_stage reads done before x write / h_lds zero
    x_lds[tq * 64 + px]       = xacc.x;
    x_lds[(tq + 4) * 64 + px] = xacc.y;
    // zero h state (aliases h_stage)
    #pragma unroll
    for (int i = 0; i < 9; ++i) {
        int idx = tid + 256 * i;
        if (idx < 2304) ((unsigned*)uni)[idx] = 0u;
    }
    __syncthreads();

    unsigned short* hrow = h_lds + wv * 16 * 72;
    int pw = p0 + wv * 16;
    float bs = b_s_p[0];

    float c_st[4][4];
    #pragma unroll
    for (int hb = 0; hb < 4; ++hb)
        #pragma unroll
        for (int r = 0; r < 4; ++r) c_st[hb][r] = 0.0f;

    for (int t = 0; t < TT; ++t) {
        halfx8 a0 = *(const halfx8*)(hrow + s * 72 + q * 8);        // k = 0..31
        halfx8 a1 = *(const halfx8*)(hrow + s * 72 + q * 8 + 32);   // k = 32..63

        // s_{t-1} = h_t @ w_s via MFMA (col 0 only); lanes s==0 hold seq q*4+r
        if (t > 0) {
            floatx4 sa = {0.f, 0.f, 0.f, 0.f};
            sa = __builtin_amdgcn_mfma_f32_16x16x32_f16(a0, bfr[32], sa, 0, 0, 0);
            sa = __builtin_amdgcn_mfma_f32_16x16x32_f16(a1, bfr[33], sa, 0, 0, 0);
            if (s == 0) {
                floatx4 o4 = {sa[0] + bs, sa[1] + bs, sa[2] + bs, sa[3] + bs};
                *(floatx4*)&s_buf[(bg * 8 + (t - 1)) * HW + pw + q * 4] = o4;
            }
        }

        floatx4 xv = *(const floatx4*)&x_lds[t * 64 + wv * 16 + q * 4];
        floatx2 xlo; xlo.x = xv[0]; xlo.y = xv[1];
        floatx2 xhi; xhi.x = xv[2]; xhi.y = xv[3];

        #pragma unroll
        for (int hb = 0; hb < 4; ++hb) {
            floatx4 acc[4];
            #pragma unroll
            for (int gi = 0; gi < 4; ++gi) {
                int nb = hb + 4 * gi;
                floatx2 wb = wxb_lds[s + 16 * nb];
                floatx2 lo = xlo * wb.x + wb.y;     // x*w_x + bias as C init (pk_fma)
                floatx2 hi = xhi * wb.x + wb.y;
                floatx4 a = {lo.x, lo.y, hi.x, hi.y};
                a = __builtin_amdgcn_mfma_f32_16x16x32_f16(a0, bfr[nb * 2 + 0], a, 0, 0, 0);
                a = __builtin_amdgcn_mfma_f32_16x16x32_f16(a1, bfr[nb * 2 + 1], a, 0, 0, 0);
                acc[gi] = a;
            }
            int s16 = s + 16 * hb;
            #pragma unroll
            for (int p = 0; p < 2; ++p) {
                int r0 = 2 * p;
                floatx2 iv; iv.x = acc[0][r0]; iv.y = acc[0][r0 + 1]; iv = fsig2(iv);
                floatx2 fv; fv.x = acc[1][r0]; fv.y = acc[1][r0 + 1]; fv = fsig2(fv);
                floatx2 gv; gv.x = acc[2][r0]; gv.y = acc[2][r0 + 1]; gv = ftanh2(gv);
                floatx2 ov; ov.x = acc[3][r0]; ov.y = acc[3][r0 + 1]; ov = fsig2(ov);
                floatx2 cp; cp.x = c_st[hb][r0]; cp.y = c_st[hb][r0 + 1];
                floatx2 c = fv * cp + iv * gv;
                c_st[hb][r0] = c.x; c_st[hb][r0 + 1] = c.y;
                floatx2 hn = ov * ftanh2(c);
                h16u u0, u1;
                u0.f = (_Float16)hn.x;
                u1.f = (_Float16)hn.y;
                hrow[(q * 4 + r0) * 72 + s16]     = u0.u;   // state for t+1
                hrow[(q * 4 + r0 + 1) * 72 + s16] = u1.u;
            }
        }
    }
    // final s_7 from h_8
    {
        halfx8 a0 = *(const halfx8*)(hrow + s * 72 + q * 8);
        halfx8 a1 = *(const halfx8*)(hrow + s * 72 + q * 8 + 32);
        floatx4 sa = {0.f, 0.f, 0.f, 0.f};
        sa = __builtin_amdgcn_mfma_f32_16x16x32_f16(a0, bfr[32], sa, 0, 0, 0);
        sa = __builtin_amdgcn_mfma_f32_16x16x32_f16(a1, bfr[33], sa, 0, 0, 0);
        if (s == 0) {
            floatx4 o4 = {sa[0] + bs, sa[1] + bs, sa[2] + bs, sa[3] + bs};
            *(floatx4*)&s_buf[(bg * 8 + 7) * HW + pw + q * 4] = o4;
        }
    }
}

// ---------------- conv_out: 1x1 conv with pk-fma ----------------
__global__ __launch_bounds__(256) void conv_out_kernel(
    const float* __restrict__ x, const float* __restrict__ Wt,
    const float* __restrict__ bias, float* __restrict__ y) {
    int p  = blockIdx.x * 256 + threadIdx.x;
    int b  = blockIdx.y;
    int oh = blockIdx.z;                  // outputs [32*oh, 32*oh+32)
    const float* xb = x + b * 64 * HW;
    const floatx2* Wt2 = (const floatx2*)Wt;  // row c: 32 float2 pairs
    floatx2 acc[16];
    #pragma unroll
    for (int j = 0; j < 16; ++j) { acc[j].x = 0.f; acc[j].y = 0.f; }
    #pragma unroll 4
    for (int c = 0; c < 64; ++c) {
        float hv = xb[c * HW + p];
        floatx2 h2; h2.x = hv; h2.y = hv;
        #pragma unroll
        for (int j = 0; j < 16; ++j)
            acc[j] = acc[j] + Wt2[c * 32 + oh * 16 + j] * h2;
    }
    float* yb = y + b * 64 * HW + oh * 32 * HW;
    #pragma unroll
    for (int j = 0; j < 16; ++j) {
        yb[(2 * j) * HW + p]     = acc[j].x + bias[oh * 32 + 2 * j];
        yb[(2 * j + 1) * HW + p] = acc[j].y + bias[oh * 32 + 2 * j + 1];
    }
}

extern "C" void kernel_launch(void* const* d_in, const int* in_sizes, int n_in,
                              void* d_out, int out_size, void* d_ws, size_t ws_size,
                              hipStream_t stream) {
    const float* h     = (const float*)d_in[0];
    const float* w_in  = (const float*)d_in[1];
    const float* b_in  = (const float*)d_in[2];
    const float* w_ih  = (const float*)d_in[3];
    const float* w_hh  = (const float*)d_in[4];
    const float* b_ih  = (const float*)d_in[5];
    const float* b_hh  = (const float*)d_in[6];
    const float* w_s   = (const float*)d_in[7];
    const float* b_s   = (const float*)d_in[8];
    const float* w_out = (const float*)d_in[9];
    const float* b_out = (const float*)d_in[10];
    float* out = (float*)d_out;
    float* ws  = (float*)d_ws;

    prep_kernel<<<2, 256, 0, stream>>>(w_ih, w_hh, b_ih, b_hh, w_s, w_out, ws);
    // fused conv_in + LSTM: hin -> s_buf (ws)
    lstm_kernel<<<4096, 256, 0, stream>>>(h, ws, ws + OFF_SBUF, w_in, b_in, b_s);
    // conv_out: s_buf -> d_out
    conv_out_kernel<<<dim3(16, BB, 2), 256, 0, stream>>>(ws + OFF_SBUF, ws + OFF_WTOUT, b_out, out);
}